// Round 13
// baseline (138.714 us; speedup 1.0000x reference)
//
#include <hip/hip_runtime.h>
#include <hip/hip_bf16.h>

#define RANK 16
#define BATCH 32768
#define K_DIM 4096   // A1*B1
#define N_DIM 64     // A2*B2
#define CHUNK 256    // K floats per chunk = 1KB fp32 per row (best rate, r6)
#define NCHUNK 16    // 4096/256
#define ROWB 64      // rows per block (r7's proven w amortization)

typedef __bf16 bf16x8 __attribute__((ext_vector_type(8)));
typedef float floatx4 __attribute__((ext_vector_type(4)));
typedef unsigned short bfu4 __attribute__((ext_vector_type(4)));

#define WAITVM(n)  asm volatile("s_waitcnt vmcnt(" #n ")" ::: "memory")
#define WAITLGKM() asm volatile("s_waitcnt lgkmcnt(0)" ::: "memory")
#define BARRIER()  asm volatile("s_barrier" ::: "memory")

__device__ inline unsigned short f2bf(float f) {
  unsigned u = __builtin_bit_cast(unsigned, f);
  u += 0x7fffu + ((u >> 16) & 1u);   // round-to-nearest-even
  return (unsigned short)(u >> 16);
}

// Fragment-major w for the 16x16x32 B-operand (layout as r7):
//   wF[((cg*128 + ks)*64 + lane)*8 + j] = w[k][n],
//   n = cg*16 + (lane&15), k = ks*32 + (lane>>4)*8 + j.
__global__ __launch_bounds__(256) void build_wF(
    const float* __restrict__ s, const float* __restrict__ a,
    const float* __restrict__ b, unsigned short* __restrict__ wF) {
  int e = blockIdx.x * 256 + threadIdx.x;   // 0 .. 262143
  int j    = e & 7;
  int lane = (e >> 3) & 63;
  int ks   = (e >> 9) & 127;
  int cg   = e >> 16;
  int n = cg * 16 + (lane & 15);
  int k = ks * 32 + ((lane >> 4) << 3) + j;
  int i = k >> 6, kk = k & 63, jj = n >> 3, ll = n & 7;
  float acc = 0.f;
  #pragma unroll
  for (int r = 0; r < RANK; ++r) {
    acc += a[r * 512 + i * 8 + jj] * b[r * 512 + kk * 8 + ll];
  }
  acc *= s[i * 8 + jj];
  wF[e] = f2bf(acc);
}

// Round-13 = round-12 with the ushort4 name collision fixed (bfu4).
// r7 skeleton (64 rows x 64 cols, 4 waves = one 16-col group each,
// 512 blocks = 2 independent 256-thr blocks/CU, frag-major w in regs)
// with the staging path rebuilt:
//  - CHUNK=256 -> 1KB contiguous x reads per row (r6 demonstrated the
//    best port rate, 12.7 B/cyc, at this run length; its loss was w
//    duplication, which this keeps amortized like r7).
//  - x staged as BF16 via reg-staging (coalesced dwordx4 -> cvt ->
//    swizzled ds_write): halves LDS (2x32KB fits 2 blk/CU), halves
//    ds_read count (1 b128 = 1 full A-frag), and removes the 4x
//    redundant f32->bf16 cvt from the compute phase.
//  - LDS swizzle: additive rotation, phys_unit = (unit + 2*(row&15))&31.
//    Reads: 2 lanes/unit exactly (b128 wave64 floor). Writes: bijective.
//    Reg-staged, so swizzle is applied on both sides by construction.
//  - One barrier per chunk (16 total): compute(cur) -> waitvm ->
//    ds_write(next) -> issue loads(next+1) -> lgkmcnt(0) -> barrier.
__global__ __launch_bounds__(256, 2) void kron_gemm(
    const float* __restrict__ x, const unsigned short* __restrict__ wF,
    const float* __restrict__ bias, float* __restrict__ out) {
  __shared__ __align__(16) __bf16 As[2][ROWB * CHUNK];   // 2 x 32 KB

  const int tid  = threadIdx.x;
  const int lane = tid & 63;
  const int wave = tid >> 6;     // = col-group cg
  const int ln15 = lane & 15;
  const int kseg = lane >> 4;
  const int m0   = blockIdx.x * ROWB;

  floatx4 acc[4] = {};

  struct W8  { bf16x8 t[8]; };
  struct X16 { float4 v[16]; };

  // w frags for one chunk (8 K-steps of 32): 8 x 1KB contiguous loads
  auto loadw = [&](int c) {
    W8 w;
    #pragma unroll
    for (int t = 0; t < 8; ++t)
      w.t[t] = *(const bf16x8*)(wF + (((size_t)(wave * 128 + c * 8 + t)) << 9)
                                + (lane << 3));
    return w;
  };

  // x chunk c for this wave's 16 rows: 16 coalesced 1KB loads to regs
  auto loadx = [&](int c) {
    X16 xv;
    #pragma unroll
    for (int j = 0; j < 16; ++j)
      xv.v[j] = *(const float4*)(x + (size_t)(m0 + wave * 16 + j) * K_DIM
                                 + c * CHUNK + 4 * lane);
    return xv;
  };

  // cvt + swizzled ds_write of 16 rows x 512B bf16
  auto writeAs = [&](int buf, const X16& xv) {
    char* Ab = (char*)&As[buf][0];
    const int u    = lane >> 1;
    const int half = lane & 1;
    #pragma unroll
    for (int j = 0; j < 16; ++j) {
      bfu4 o;
      o[0] = f2bf(xv.v[j].x); o[1] = f2bf(xv.v[j].y);
      o[2] = f2bf(xv.v[j].z); o[3] = f2bf(xv.v[j].w);
      const int phys = (u + 2 * j) & 31;     // row&15 == j (wave*16 ≡ 0 mod 16)
      *(bfu4*)(Ab + (wave * 16 + j) * 512 + phys * 16 + half * 8) = o;
    }
  };

  // compute chunk in buffer buf: 32 ds_read_b128 + 32 MFMA, no vmem
  auto compute = [&](int buf, const W8& w) {
    const char* Ab = (const char*)&As[buf][0];
    #pragma unroll
    for (int t = 0; t < 8; ++t) {
      #pragma unroll
      for (int f = 0; f < 4; ++f) {
        const int row  = f * 16 + ln15;
        const int phys = (4 * t + kseg + 2 * ln15) & 31;
        bf16x8 af = *(const bf16x8*)(Ab + row * 512 + phys * 16);
        acc[f] = __builtin_amdgcn_mfma_f32_16x16x32_bf16(af, w.t[t],
                                                         acc[f], 0, 0, 0);
      }
    }
  };

  // ---- prologue: chunk 0 staged, chunk 1 in flight ----
  W8 wA = loadw(0);
  X16 xA = loadx(0);
  WAITVM(0);
  writeAs(0, xA);
  W8 wB = loadw(1);
  xA = loadx(1);
  WAITLGKM();
  BARRIER();              // As0 = chunk 0 visible

  // ---- main loop: 2 chunks per iteration, static even/odd roles ----
  // invariant at top (c=2i): As0=chunk c visible; wA=w(c); wB=w(c+1);
  // xA = x(c+1) in flight.
  #pragma unroll 1
  for (int i = 0; i < 7; ++i) {
    const int c = 2 * i;
    compute(0, wA);
    WAITVM(0);                    // x(c+1) (and w(c+1)) arrived
    writeAs(1, xA);               // safe: all waves past barrier after
                                  // their last As1 read (chunk c-1)
    wA = loadw(c + 2);
    xA = loadx(c + 2);
    WAITLGKM();
    BARRIER();                    // As1 = chunk c+1 visible

    compute(1, wB);
    WAITVM(0);                    // x(c+2), w(c+2) arrived
    writeAs(0, xA);
    wB = loadw(c + 3);
    xA = loadx(c + 3);
    WAITLGKM();
    BARRIER();                    // As0 = chunk c+2 visible
  }
  // ---- tail: chunks 14, 15 (wA=w14, wB=w15, xA=x(15) in flight) ----
  compute(0, wA);
  WAITVM(0);
  writeAs(1, xA);
  WAITLGKM();
  BARRIER();
  compute(1, wB);

  // ---- epilogue: bounce through LDS for coalesced out stores ----
  // D mapping: col=lane&15 (in group), row=(lane>>4)*4+r (m89 mapping).
  BARRIER();                      // all waves done with As
  float* A0 = (float*)&As[0][0];  // 16KB bounce buffer
  const int col = wave * 16 + ln15;
  const float bv = bias[col];
  #pragma unroll
  for (int f = 0; f < 4; ++f) {
    #pragma unroll
    for (int r = 0; r < 4; ++r)
      A0[(f * 16 + kseg * 4 + r) * N_DIM + col] = acc[f][r] + bv;
  }
  __syncthreads();
  // 64 rows x 64 cols x 4B = 16 KB contiguous at out + m0*64
  float4* og = (float4*)(out + (size_t)m0 * N_DIM);
  const float4* ol = (const float4*)A0;
  #pragma unroll
  for (int p = 0; p < 4; ++p) {
    const int fi = p * 256 + tid;
    og[fi] = ol[fi];
  }
}

extern "C" void kernel_launch(void* const* d_in, const int* in_sizes, int n_in,
                              void* d_out, int out_size, void* d_ws, size_t ws_size,
                              hipStream_t stream) {
  const float* x    = (const float*)d_in[0];
  const float* s    = (const float*)d_in[1];
  const float* a    = (const float*)d_in[2];
  const float* b    = (const float*)d_in[3];
  const float* bias = (const float*)d_in[4];
  float* out = (float*)d_out;
  unsigned short* wF = (unsigned short*)d_ws;   // 512 KB

  build_wF<<<1024, 256, 0, stream>>>(s, a, b, wF);
  kron_gemm<<<BATCH / ROWB, 256, 0, stream>>>(x, wF, bias, out);
}

// Round 14
// 121.253 us; speedup vs baseline: 1.1440x; 1.1440x over previous
//
#include <hip/hip_runtime.h>
#include <hip/hip_bf16.h>

#define RANK 16
#define BATCH 32768
#define K_DIM 4096   // A1*B1
#define N_DIM 64     // A2*B2
#define CHUNK 128    // K floats per chunk = 512B per row
#define NCHUNK 32    // 4096/128
#define ROWB 64      // rows per block

typedef __bf16 bf16x8 __attribute__((ext_vector_type(8)));
typedef float floatx4 __attribute__((ext_vector_type(4)));
typedef unsigned short ushort8 __attribute__((ext_vector_type(8)));

#define WAITVM(n) asm volatile("s_waitcnt vmcnt(" #n ")" ::: "memory")
#define BARRIER() asm volatile("s_barrier" ::: "memory")

__device__ inline unsigned short f2bf(float f) {
  unsigned u = __builtin_bit_cast(unsigned, f);
  u += 0x7fffu + ((u >> 16) & 1u);   // round-to-nearest-even
  return (unsigned short)(u >> 16);
}

__device__ inline bf16x8 cvt8(float4 a0, float4 a1) {
  ushort8 au;
  au[0] = f2bf(a0.x); au[1] = f2bf(a0.y); au[2] = f2bf(a0.z); au[3] = f2bf(a0.w);
  au[4] = f2bf(a1.x); au[5] = f2bf(a1.y); au[6] = f2bf(a1.z); au[7] = f2bf(a1.w);
  return __builtin_bit_cast(bf16x8, au);
}

// Fragment-major w for the 16x16x32 B-operand (layout unchanged):
//   wF[((cg*128 + ks)*64 + lane)*8 + j] = w[k][n],
//   n = cg*16 + (lane&15), k = ks*32 + (lane>>4)*8 + j.
__global__ __launch_bounds__(256) void build_wF(
    const float* __restrict__ s, const float* __restrict__ a,
    const float* __restrict__ b, unsigned short* __restrict__ wF) {
  int e = blockIdx.x * 256 + threadIdx.x;   // 0 .. 262143
  int j    = e & 7;
  int lane = (e >> 3) & 63;
  int ks   = (e >> 9) & 127;
  int cg   = e >> 16;
  int n = cg * 16 + (lane & 15);
  int k = ks * 32 + ((lane >> 4) << 3) + j;
  int i = k >> 6, kk = k & 63, jj = n >> 3, ll = n & 7;
  float acc = 0.f;
  #pragma unroll
  for (int r = 0; r < RANK; ++r) {
    acc += a[r * 512 + i * 8 + jj] * b[r * 512 + kk * 8 + ll];
  }
  acc *= s[i * 8 + jj];
  wF[e] = f2bf(acc);
}

// Round-14 = round-7 byte-identical (the only structure that won: 64
// rows x 64 cols, 4 waves = one 16-col group each, 2 blocks/CU, gll
// staging at 512B runs, w in regs, WAITVM(12) counted ring) with ONE
// change: the scattered 4B-store epilogue replaced by the r8/r9/r10-
// validated LDS-bounce + contiguous float4 stream-out. Single-variable
// A/B against r7's 121us.
__global__ __launch_bounds__(256, 2) void kron_gemm(
    const float* __restrict__ x, const unsigned short* __restrict__ wF,
    const float* __restrict__ bias, float* __restrict__ out) {
  __shared__ __align__(16) float As[2][ROWB * CHUNK];   // 2 x 32 KB

  const int tid  = threadIdx.x;
  const int lane = tid & 63;
  const int wave = tid >> 6;     // = col-group cg
  const int ln15 = lane & 15;
  const int kseg = lane >> 4;
  const int m0   = blockIdx.x * ROWB;
  const int rhalf = lane >> 5;   // staging: row within the 1KB pair

  floatx4 acc[4] = {};

  struct W4 { bf16x8 t[4]; };

  auto loadw = [&](int c) {
    W4 w;
    #pragma unroll
    for (int t = 0; t < 4; ++t)
      w.t[t] = *(const bf16x8*)(wF + (((size_t)(wave * 128 + c * 4 + t)) << 9)
                                + (lane << 3));
    return w;
  };

  // stage chunk c: 8 gll instrs/wave, each 1KB = 2 rows x 512B
  auto stage = [&](float* buf, int c) {
    #pragma unroll
    for (int p = 0; p < 8; ++p) {
      const int rbase = wave * 16 + 2 * p;               // wave-uniform
      const int row   = rbase + rhalf;                   // per-lane
      const int sb    = ((lane & 31) << 4) ^ ((row & 7) << 4);
      const float* src = x + (size_t)(m0 + row) * K_DIM + c * CHUNK + (sb >> 2);
      float* dst = buf + rbase * CHUNK;
      __builtin_amdgcn_global_load_lds(
          (const __attribute__((address_space(1))) void*)(const void*)src,
          (__attribute__((address_space(3))) void*)(void*)dst, 16, 0, 0);
    }
  };

  auto compute = [&](const float* buf, const W4& w) {
    const char* Ab = (const char*)buf;
    #pragma unroll
    for (int t = 0; t < 4; ++t) {
      #pragma unroll
      for (int f = 0; f < 4; ++f) {
        const int row = f * 16 + ln15;
        const int swz = (row & 7) << 4;
        const int b0  = t * 128 + kseg * 32;
        float4 lo = *(const float4*)(Ab + row * 512 + ((b0)      ^ swz));
        float4 hi = *(const float4*)(Ab + row * 512 + ((b0 + 16) ^ swz));
        acc[f] = __builtin_amdgcn_mfma_f32_16x16x32_bf16(cvt8(lo, hi), w.t[t],
                                                         acc[f], 0, 0, 0);
      }
    }
  };

  float* A0 = &As[0][0];
  float* A1 = &As[1][0];

  // ---- prologue: chunk 0 in flight ----
  W4 wA = loadw(0);
  stage(A0, 0);

  // ---- main loop: 2 chunks per iteration, static even/odd roles ----
  #pragma unroll 1
  for (int i = 0; i < 15; ++i) {
    const int c = 2 * i;
    W4 wB = loadw(c + 1);
    stage(A1, c + 1);
    WAITVM(12);            // chunk c landed; c+1's 12 ops stay in flight
    BARRIER();
    compute(A0, wA);
    BARRIER();             // all waves done reading A0

    wA = loadw(c + 2);
    stage(A0, c + 2);
    WAITVM(12);
    BARRIER();
    compute(A1, wB);
    BARRIER();
  }
  // ---- tail: chunks 30, 31 ----
  {
    W4 wB = loadw(31);
    stage(A1, 31);
    WAITVM(12);
    BARRIER();
    compute(A0, wA);
    BARRIER();
    WAITVM(0);
    BARRIER();
    compute(A1, wB);
  }

  // ---- epilogue: bounce through LDS for coalesced out stores ----
  // D mapping: col=lane&15 (in group), row=(lane>>4)*4+r (m89 mapping).
  // As[0] is free: every wave's last As[0] read (chunk 30) is behind a
  // barrier; tail reads hit As[1] only (disjoint).
  const int col = wave * 16 + ln15;
  const float bv = bias[col];
  #pragma unroll
  for (int f = 0; f < 4; ++f) {
    #pragma unroll
    for (int r = 0; r < 4; ++r)
      A0[(f * 16 + kseg * 4 + r) * N_DIM + col] = acc[f][r] + bv;
  }
  __syncthreads();
  // 64 rows x 64 cols x 4B = 16 KB contiguous at out + m0*64
  float4* og = (float4*)(out + (size_t)m0 * N_DIM);
  const float4* ol = (const float4*)A0;
  #pragma unroll
  for (int p = 0; p < 4; ++p) {
    const int fi = p * 256 + tid;
    og[fi] = ol[fi];
  }
}

extern "C" void kernel_launch(void* const* d_in, const int* in_sizes, int n_in,
                              void* d_out, int out_size, void* d_ws, size_t ws_size,
                              hipStream_t stream) {
  const float* x    = (const float*)d_in[0];
  const float* s    = (const float*)d_in[1];
  const float* a    = (const float*)d_in[2];
  const float* b    = (const float*)d_in[3];
  const float* bias = (const float*)d_in[4];
  float* out = (float*)d_out;
  unsigned short* wF = (unsigned short*)d_ws;   // 512 KB

  build_wF<<<1024, 256, 0, stream>>>(s, a, b, wF);
  kron_gemm<<<BATCH / ROWB, 256, 0, stream>>>(x, wF, bias, out);
}